// Round 8
// baseline (86.362 us; speedup 1.0000x reference)
//
#include <hip/hip_runtime.h>

// out = relu((x @ B^T) * A^T + bias)  -- rank-1 reassociated form.
// x: [8192, 2048] f32, A: [10000,1] f32, B: [1,2048] f32, bias: [10000] f32
// out: [8192, 10000] f32
//
// Wave-per-row fused kernel. Theory from R3..R6: per-wave store stream must
// be a SINGLE linear run (DRAM page locality) -- R3's 2-stream interleave beat
// R4's 4-stream and R6's 32-stream shapes; fillBuffer (1 linear stream) hits
// 7 TB/s. R5 had the right shape but only ~8 waves/CU (VGPR-fat pipeline).
// Here: no LDS, no barriers, lean regs (launch_bounds(256,8) -> <=64 VGPR,
// 32 waves/CU), 2048 blocks. NT stores (R3: +37%) + NT x loads.

#define BATCH       8192
#define IN_FEATURES 2048
#define N_CLASSES   10000
#define NC4         2500   // N_CLASSES/4
#define BLOCK       256
#define WPB         4      // waves per block (= rows per block)
#define GRID        (BATCH / WPB)   // 2048

typedef float fx4 __attribute__((ext_vector_type(4)));

__global__ __launch_bounds__(BLOCK, 8) void lora_waverow_kernel(
    const float* __restrict__ x,
    const float* __restrict__ A,
    const float* __restrict__ B,
    const float* __restrict__ bias,
    float* __restrict__ out)
{
    const int lane = threadIdx.x & 63;
    const int wid  = threadIdx.x >> 6;
    const int row  = blockIdx.x * WPB + wid;

    const fx4* __restrict__ xr = reinterpret_cast<const fx4*>(x + (size_t)row * IN_FEATURES);
    const fx4* __restrict__ B4 = reinterpret_cast<const fx4*>(B);

    // ---- dot(x[row,:], B) : 8 f4 per lane, loads interleaved with fma ----
    float acc = 0.0f;
    #pragma unroll
    for (int k = 0; k < 8; ++k) {
        fx4 xv = __builtin_nontemporal_load(&xr[lane + 64 * k]);
        fx4 bv = B4[lane + 64 * k];
        acc = fmaf(xv.x, bv.x, acc);
        acc = fmaf(xv.y, bv.y, acc);
        acc = fmaf(xv.z, bv.z, acc);
        acc = fmaf(xv.w, bv.w, acc);
    }

    // butterfly reduce: every lane ends with the full sum (no broadcast needed)
    #pragma unroll
    for (int off = 32; off > 0; off >>= 1)
        acc += __shfl_xor(acc, off, 64);
    const float s = acc;

    // ---- stream the 40KB output row: ONE linear NT store stream per wave ----
    const fx4* __restrict__ A4  = reinterpret_cast<const fx4*>(A);
    const fx4* __restrict__ bb4 = reinterpret_cast<const fx4*>(bias);
    fx4* __restrict__ o = reinterpret_cast<fx4*>(out) + (size_t)row * NC4;

    for (int j = lane; j < NC4; j += 64) {
        fx4 a = A4[j];
        fx4 b = bb4[j];
        fx4 v;
        v.x = fmaxf(fmaf(s, a.x, b.x), 0.0f);
        v.y = fmaxf(fmaf(s, a.y, b.y), 0.0f);
        v.z = fmaxf(fmaf(s, a.z, b.z), 0.0f);
        v.w = fmaxf(fmaf(s, a.w, b.w), 0.0f);
        __builtin_nontemporal_store(v, &o[j]);
    }
}

extern "C" void kernel_launch(void* const* d_in, const int* in_sizes, int n_in,
                              void* d_out, int out_size, void* d_ws, size_t ws_size,
                              hipStream_t stream) {
    const float* x    = (const float*)d_in[0];
    const float* A    = (const float*)d_in[1];
    const float* B    = (const float*)d_in[2];
    const float* bias = (const float*)d_in[3];
    float* out        = (float*)d_out;

    lora_waverow_kernel<<<GRID, BLOCK, 0, stream>>>(x, A, B, bias, out);
}

// Round 9
// 63.928 us; speedup vs baseline: 1.3509x; 1.3509x over previous
//
#include <hip/hip_runtime.h>

// out = relu((x @ B^T) * A^T + bias)  -- rank-1 reassociated form.
// x: [8192, 2048] f32, A: [10000,1] f32, B: [1,2048] f32, bias: [10000] f32
// out: [8192, 10000] f32
//
// Block-per-row, BARRIER-FREE fused kernel. 8192 blocks (32/CU -> 4 resident
// generations; R3..R7 showed generation-overlap of read/write phases is the
// lever). All 4 waves of a block redundantly compute the row dot (full row
// per wave: first wave DRAM-misses, rest hit L1; VALU ~5% busy so redundant
// FLOPs free) -> butterfly reduce in-wave -> interleaved NT stores. No LDS,
// no __syncthreads, no vmcnt(0) drains; waves drift -> fine-grain R/W mix.
// NT stores proven +37% (R3). Plain cached x/A/bias loads (R3-proven).

#define BATCH       8192
#define IN_FEATURES 2048
#define N_CLASSES   10000
#define NC4         2500   // N_CLASSES/4
#define BLOCK       256

typedef float fx4 __attribute__((ext_vector_type(4)));

__global__ __launch_bounds__(BLOCK, 8) void lora_rowblock_kernel(
    const float* __restrict__ x,
    const float* __restrict__ A,
    const float* __restrict__ B,
    const float* __restrict__ bias,
    float* __restrict__ out)
{
    const int tid  = threadIdx.x;
    const int lane = tid & 63;
    const int row  = blockIdx.x;

    const fx4* __restrict__ xr = reinterpret_cast<const fx4*>(x + (size_t)row * IN_FEATURES);
    const fx4* __restrict__ B4 = reinterpret_cast<const fx4*>(B);

    // ---- dot(x[row,:], B): every wave loads the FULL row (8 f4/lane) ----
    // two 4-register chunks to keep VGPR <= 64 (32 waves/CU)
    float acc = 0.0f;
    #pragma unroll
    for (int c = 0; c < 2; ++c) {
        fx4 xv0 = xr[lane + 64 * (4 * c + 0)];
        fx4 xv1 = xr[lane + 64 * (4 * c + 1)];
        fx4 xv2 = xr[lane + 64 * (4 * c + 2)];
        fx4 xv3 = xr[lane + 64 * (4 * c + 3)];
        fx4 bv0 = B4[lane + 64 * (4 * c + 0)];
        fx4 bv1 = B4[lane + 64 * (4 * c + 1)];
        fx4 bv2 = B4[lane + 64 * (4 * c + 2)];
        fx4 bv3 = B4[lane + 64 * (4 * c + 3)];
        acc = fmaf(xv0.x, bv0.x, acc); acc = fmaf(xv0.y, bv0.y, acc);
        acc = fmaf(xv0.z, bv0.z, acc); acc = fmaf(xv0.w, bv0.w, acc);
        acc = fmaf(xv1.x, bv1.x, acc); acc = fmaf(xv1.y, bv1.y, acc);
        acc = fmaf(xv1.z, bv1.z, acc); acc = fmaf(xv1.w, bv1.w, acc);
        acc = fmaf(xv2.x, bv2.x, acc); acc = fmaf(xv2.y, bv2.y, acc);
        acc = fmaf(xv2.z, bv2.z, acc); acc = fmaf(xv2.w, bv2.w, acc);
        acc = fmaf(xv3.x, bv3.x, acc); acc = fmaf(xv3.y, bv3.y, acc);
        acc = fmaf(xv3.z, bv3.z, acc); acc = fmaf(xv3.w, bv3.w, acc);
    }

    // in-wave butterfly reduce -- every lane gets the full sum, no broadcast
    #pragma unroll
    for (int off = 32; off > 0; off >>= 1)
        acc += __shfl_xor(acc, off, 64);
    const float s = acc;

    // ---- stream out[row,:]: NT stores, 4 waves interleave at 1KB granularity ----
    const fx4* __restrict__ A4  = reinterpret_cast<const fx4*>(A);
    const fx4* __restrict__ bb4 = reinterpret_cast<const fx4*>(bias);
    fx4* __restrict__ o = reinterpret_cast<fx4*>(out) + (size_t)row * NC4;

    for (int j = tid; j < NC4; j += BLOCK) {
        fx4 a = A4[j];
        fx4 b = bb4[j];
        fx4 v;
        v.x = fmaxf(fmaf(s, a.x, b.x), 0.0f);
        v.y = fmaxf(fmaf(s, a.y, b.y), 0.0f);
        v.z = fmaxf(fmaf(s, a.z, b.z), 0.0f);
        v.w = fmaxf(fmaf(s, a.w, b.w), 0.0f);
        __builtin_nontemporal_store(v, &o[j]);
    }
}

extern "C" void kernel_launch(void* const* d_in, const int* in_sizes, int n_in,
                              void* d_out, int out_size, void* d_ws, size_t ws_size,
                              hipStream_t stream) {
    const float* x    = (const float*)d_in[0];
    const float* A    = (const float*)d_in[1];
    const float* B    = (const float*)d_in[2];
    const float* bias = (const float*)d_in[3];
    float* out        = (float*)d_out;

    lora_rowblock_kernel<<<BATCH, BLOCK, 0, stream>>>(x, A, B, bias, out);
}